// Round 9
// baseline (1281.363 us; speedup 1.0000x reference)
//
#include <hip/hip_runtime.h>
#include <math.h>

// Residual VQ: x (262144,128) fp32, codebooks (3,256,128) fp32.
// Output: [indices as float (262144*3)] ++ [quantized (262144*128)].
//
// ARITHMETIC CONTRACT (round 3, absmax=0 — do not change):
//   M_k  = OpenBLAS sgemm K-loop: sequential FMA chain j=0..127, acc init 0
//   A    = np.sum(r*r): pairwise_sum 8-accumulator scheme, products rounded
//          separately (fmaf(x,x,0) = single-rounded product, blocks fusion)
//   d2_k = (A - 2.0f*M_k) + B_k ; argmin strict < ascending k
//   residual -= q ; quantized = (q0 + q1) + q2  (elementwise fp32, ref order)
//
// ROUND 13: r11 skeleton, blocking changed 2-items/quarter -> 4-items/eighth.
// r11 accounting (1059us): per-SIMD 2.43M cyc = FMA 0.86M + ~0.5k cyc/step
// non-FMA, dominated by 32 ds_read_b128/step at ~12cyc each — codebook
// delivery is co-dominant. This round: lane o=lane&7 holds dims [16o,16o+16)
// of 4 items -> one ds_read_b128 feeds 4 items x 4 FMAs = 16:1 (r11: 8:1),
// halving LDS traffic; residual stays 64 floats/lane (r11-equal). Depth-8
// left-fold handoff via __shfl_up(.,1,16) (DPP row_shr, VALU-only; o==0
// discards carry -> segment boundaries safe). 39 steps/phase (+11% bubble).
// LDS layout slot=row*32+(c&3)*8+(c>>2): read bank = 4o -> conflict-free;
// same-o lanes across groups read identical addrs -> broadcast. Staging =
// r11's proven linear-global-read / permuted-LDS-write. waves_per_eu(2,4)
// retained (delivered VGPR=128 in r12; this kernel's peak live ~130, unlike
// r12's overflow). r12's pointer-walk + global-side permute reverted.

constexpr int kItems = 262144;
constexpr int kDim   = 128;
constexpr int kNcb   = 3;
constexpr int kK     = 256;
constexpr int kBlock = 512;          // 8 waves; 256 items/block

__device__ __forceinline__ float sq_rn(float x) {
    return __builtin_fmaf(x, x, 0.0f);   // single-rounded product, blocks contraction
}
#define F3(a, b, c) __builtin_fmaf((a), (b), (c))

// ONLY for codebook B_k staging (global reads)
__device__ __forceinline__ float np_sumsq128(const float* __restrict__ p) {
    float a0 = sq_rn(p[0]), a1 = sq_rn(p[1]), a2 = sq_rn(p[2]), a3 = sq_rn(p[3]),
          a4 = sq_rn(p[4]), a5 = sq_rn(p[5]), a6 = sq_rn(p[6]), a7 = sq_rn(p[7]);
    #pragma unroll
    for (int i = 8; i < 128; i += 8) {
        a0 = a0 + sq_rn(p[i + 0]); a1 = a1 + sq_rn(p[i + 1]);
        a2 = a2 + sq_rn(p[i + 2]); a3 = a3 + sq_rn(p[i + 3]);
        a4 = a4 + sq_rn(p[i + 4]); a5 = a5 + sq_rn(p[i + 5]);
        a6 = a6 + sq_rn(p[i + 6]); a7 = a7 + sq_rn(p[i + 7]);
    }
    return ((a0 + a1) + (a2 + a3)) + ((a4 + a5) + (a6 + a7));
}

#define ITEMS(M) M(A) M(B) M(C) M(D)

// residual: 4 items x 4 float4 (dims 16o..16o+15 of each item), all named
#define DECLR(X) float4 R##X##_0, R##X##_1, R##X##_2, R##X##_3;
#define LOADR(X) { const float4* xp_ = (const float4*)(x + i##X * (size_t)kDim) + o * 4; \
  R##X##_0 = xp_[0]; R##X##_1 = xp_[1]; R##X##_2 = xp_[2]; R##X##_3 = xp_[3]; }

// A pairwise-8 local fold: 16 terms ascending local j (=16o+4u+e), acc (4u+e)&7
// (16o % 8 == 0 -> acc index is local)
#define AFOLD2(X) \
  u0=u0+sq_rn(R##X##_0.x); u1=u1+sq_rn(R##X##_0.y); u2=u2+sq_rn(R##X##_0.z); u3=u3+sq_rn(R##X##_0.w); \
  u4=u4+sq_rn(R##X##_1.x); u5=u5+sq_rn(R##X##_1.y); u6=u6+sq_rn(R##X##_1.z); u7=u7+sq_rn(R##X##_1.w); \
  u0=u0+sq_rn(R##X##_2.x); u1=u1+sq_rn(R##X##_2.y); u2=u2+sq_rn(R##X##_2.z); u3=u3+sq_rn(R##X##_2.w); \
  u4=u4+sq_rn(R##X##_3.x); u5=u5+sq_rn(R##X##_3.y); u6=u6+sq_rn(R##X##_3.z); u7=u7+sq_rn(R##X##_3.w);

#define ASHFL() \
  u0=__shfl_up(u0,1,16); u1=__shfl_up(u1,1,16); u2=__shfl_up(u2,1,16); u3=__shfl_up(u3,1,16); \
  u4=__shfl_up(u4,1,16); u5=__shfl_up(u5,1,16); u6=__shfl_up(u6,1,16); u7=__shfl_up(u7,1,16);

// A = np.sum(r*r): 8-round SERIAL handoff along o (exact left fold, same
// u0..u7 global term order as numpy: acc m gets t(m),t(8+m),...,t(120+m)
// ascending). Valid at o==7.
#define ACOMPUTE(X, Avar) { \
  float u0=0.f,u1=0.f,u2=0.f,u3=0.f,u4=0.f,u5=0.f,u6=0.f,u7=0.f; \
  if (o == 0) { AFOLD2(X) } \
  ASHFL() if (o == 1) { AFOLD2(X) } \
  ASHFL() if (o == 2) { AFOLD2(X) } \
  ASHFL() if (o == 3) { AFOLD2(X) } \
  ASHFL() if (o == 4) { AFOLD2(X) } \
  ASHFL() if (o == 5) { AFOLD2(X) } \
  ASHFL() if (o == 6) { AFOLD2(X) } \
  ASHFL() if (o == 7) { AFOLD2(X) } \
  Avar = ((u0 + u1) + (u2 + u3)) + ((u4 + u5) + (u6 + u7)); }

// one tile row rr: 4 shared ds_read_b128 feed 4 items x 16 FMAs (ascending j:
// c_j holds dims 16o+4j..16o+4j+3, paired with R*_j elementwise x,y,z,w)
#define FOLDROW(rr) { \
  const float4 c0 = tcr[(rr)*32 +  0]; \
  const float4 c1 = tcr[(rr)*32 +  8]; \
  const float4 c2 = tcr[(rr)*32 + 16]; \
  const float4 c3 = tcr[(rr)*32 + 24]; \
  mA##rr=F3(RA_0.x,c0.x,mA##rr); mA##rr=F3(RA_0.y,c0.y,mA##rr); mA##rr=F3(RA_0.z,c0.z,mA##rr); mA##rr=F3(RA_0.w,c0.w,mA##rr); \
  mA##rr=F3(RA_1.x,c1.x,mA##rr); mA##rr=F3(RA_1.y,c1.y,mA##rr); mA##rr=F3(RA_1.z,c1.z,mA##rr); mA##rr=F3(RA_1.w,c1.w,mA##rr); \
  mA##rr=F3(RA_2.x,c2.x,mA##rr); mA##rr=F3(RA_2.y,c2.y,mA##rr); mA##rr=F3(RA_2.z,c2.z,mA##rr); mA##rr=F3(RA_2.w,c2.w,mA##rr); \
  mA##rr=F3(RA_3.x,c3.x,mA##rr); mA##rr=F3(RA_3.y,c3.y,mA##rr); mA##rr=F3(RA_3.z,c3.z,mA##rr); mA##rr=F3(RA_3.w,c3.w,mA##rr); \
  mB##rr=F3(RB_0.x,c0.x,mB##rr); mB##rr=F3(RB_0.y,c0.y,mB##rr); mB##rr=F3(RB_0.z,c0.z,mB##rr); mB##rr=F3(RB_0.w,c0.w,mB##rr); \
  mB##rr=F3(RB_1.x,c1.x,mB##rr); mB##rr=F3(RB_1.y,c1.y,mB##rr); mB##rr=F3(RB_1.z,c1.z,mB##rr); mB##rr=F3(RB_1.w,c1.w,mB##rr); \
  mB##rr=F3(RB_2.x,c2.x,mB##rr); mB##rr=F3(RB_2.y,c2.y,mB##rr); mB##rr=F3(RB_2.z,c2.z,mB##rr); mB##rr=F3(RB_2.w,c2.w,mB##rr); \
  mB##rr=F3(RB_3.x,c3.x,mB##rr); mB##rr=F3(RB_3.y,c3.y,mB##rr); mB##rr=F3(RB_3.z,c3.z,mB##rr); mB##rr=F3(RB_3.w,c3.w,mB##rr); \
  mC##rr=F3(RC_0.x,c0.x,mC##rr); mC##rr=F3(RC_0.y,c0.y,mC##rr); mC##rr=F3(RC_0.z,c0.z,mC##rr); mC##rr=F3(RC_0.w,c0.w,mC##rr); \
  mC##rr=F3(RC_1.x,c1.x,mC##rr); mC##rr=F3(RC_1.y,c1.y,mC##rr); mC##rr=F3(RC_1.z,c1.z,mC##rr); mC##rr=F3(RC_1.w,c1.w,mC##rr); \
  mC##rr=F3(RC_2.x,c2.x,mC##rr); mC##rr=F3(RC_2.y,c2.y,mC##rr); mC##rr=F3(RC_2.z,c2.z,mC##rr); mC##rr=F3(RC_2.w,c2.w,mC##rr); \
  mC##rr=F3(RC_3.x,c3.x,mC##rr); mC##rr=F3(RC_3.y,c3.y,mC##rr); mC##rr=F3(RC_3.z,c3.z,mC##rr); mC##rr=F3(RC_3.w,c3.w,mC##rr); \
  mD##rr=F3(RD_0.x,c0.x,mD##rr); mD##rr=F3(RD_0.y,c0.y,mD##rr); mD##rr=F3(RD_0.z,c0.z,mD##rr); mD##rr=F3(RD_0.w,c0.w,mD##rr); \
  mD##rr=F3(RD_1.x,c1.x,mD##rr); mD##rr=F3(RD_1.y,c1.y,mD##rr); mD##rr=F3(RD_1.z,c1.z,mD##rr); mD##rr=F3(RD_1.w,c1.w,mD##rr); \
  mD##rr=F3(RD_2.x,c2.x,mD##rr); mD##rr=F3(RD_2.y,c2.y,mD##rr); mD##rr=F3(RD_2.z,c2.z,mD##rr); mD##rr=F3(RD_2.w,c2.w,mD##rr); \
  mD##rr=F3(RD_3.x,c3.x,mD##rr); mD##rr=F3(RD_3.y,c3.y,mD##rr); mD##rr=F3(RD_3.z,c3.z,mD##rr); mD##rr=F3(RD_3.w,c3.w,mD##rr); }

// finals: ascending k (rr 0..3), strict <; (A-2m)+B bit-safe (2m exact)
#define FINX(X, Avar, bestv, biv) { \
  float d_; \
  d_=(Avar-2.0f*m##X##0)+bb.x; if(d_<bestv){bestv=d_; biv=kb+0;} \
  d_=(Avar-2.0f*m##X##1)+bb.y; if(d_<bestv){bestv=d_; biv=kb+1;} \
  d_=(Avar-2.0f*m##X##2)+bb.z; if(d_<bestv){bestv=d_; biv=kb+2;} \
  d_=(Avar-2.0f*m##X##3)+bb.w; if(d_<bestv){bestv=d_; biv=kb+3;} }

#define CSHFL(X) \
  v##X##0=__shfl_up(m##X##0,1,16); v##X##1=__shfl_up(m##X##1,1,16); \
  v##X##2=__shfl_up(m##X##2,1,16); v##X##3=__shfl_up(m##X##3,1,16);

// residual -= q (elementwise, ref order): this lane's 16 dims of item X
#define UPDR(X, selv) { \
  const float4* cw_ = (const float4*)(cb + ((size_t)c * kK + (selv)) * kDim) + o * 4; \
  R##X##_0.x-=cw_[0].x; R##X##_0.y-=cw_[0].y; R##X##_0.z-=cw_[0].z; R##X##_0.w-=cw_[0].w; \
  R##X##_1.x-=cw_[1].x; R##X##_1.y-=cw_[1].y; R##X##_1.z-=cw_[1].z; R##X##_1.w-=cw_[1].w; \
  R##X##_2.x-=cw_[2].x; R##X##_2.y-=cw_[2].y; R##X##_2.z-=cw_[2].z; R##X##_2.w-=cw_[2].w; \
  R##X##_3.x-=cw_[3].x; R##X##_3.y-=cw_[3].y; R##X##_3.z-=cw_[3].z; R##X##_3.w-=cw_[3].w; }

// quantized output: ((0+q0)+q1)+q2, fp32 elementwise, lane's 16 dims
#define OUTQ(X, s0v, s1v, s2v, itemv) { \
  const float4* g0_ = (const float4*)(cb + ((size_t)0 * kK + (s0v)) * kDim) + o * 4; \
  const float4* g1_ = (const float4*)(cb + ((size_t)1 * kK + (s1v)) * kDim) + o * 4; \
  const float4* g2_ = (const float4*)(cb + ((size_t)2 * kK + (s2v)) * kDim) + o * 4; \
  float4* qo_ = (float4*)(out_q + (itemv) * kDim) + o * 4; \
  _Pragma("unroll") \
  for (int u = 0; u < 4; ++u) { \
    const float4 v0 = g0_[u], v1 = g1_[u], v2 = g2_[u]; \
    float4 w_; \
    w_.x=(v0.x+v1.x)+v2.x; w_.y=(v0.y+v1.y)+v2.y; \
    w_.z=(v0.z+v1.z)+v2.z; w_.w=(v0.w+v1.w)+v2.w; \
    qo_[u]=w_; } }

__global__ __launch_bounds__(kBlock)
__attribute__((amdgpu_waves_per_eu(2, 4)))
void rvq_kernel(
    const float* __restrict__ x,
    const float* __restrict__ cb,
    float* __restrict__ out)
{
    extern __shared__ float4 s_cb[];        // 4096 float4 = 64 KiB: one phase,
                                            // slot = row*32 + (col&3)*8 + (col>>2)
    __shared__ float4 s_B4[kNcb * kK / 4];  // 3 KiB

    const int tid  = threadIdx.x;
    const int lane = tid & 63;
    const int o    = lane & 7;              // dim-eighth 0..7
    const int grp  = lane >> 3;             // item-group 0..7 (4 items each)
    const int wave = tid >> 6;              // 0..7

    // B_k = np.sum(cb*cb, axis=-1), bit-exact
    for (int m = tid; m < kNcb * kK; m += kBlock)
        ((float*)s_B4)[m] = np_sumsq128(cb + (size_t)m * kDim);

    const size_t iA = (size_t)blockIdx.x * 256 + wave * 32 + grp * 4 + 0;
    const size_t iB = iA + 1, iC = iA + 2, iD = iA + 3;

    ITEMS(DECLR)
    ITEMS(LOADR)

    float Aa, Ab, Ac, Ad;
    ACOMPUTE(A, Aa) ACOMPUTE(B, Ab) ACOMPUTE(C, Ac) ACOMPUTE(D, Ad)

    int sA0=0,sA1=0,sA2=0,sB0=0,sB1=0,sB2=0,sC0=0,sC1=0,sC2=0,sD0=0,sD1=0,sD2=0;

    #pragma unroll
    for (int c = 0; c < kNcb; ++c) {
        float bestA = INFINITY, bestB = INFINITY, bestC = INFINITY, bestD = INFINITY;
        int   biA = 0, biB = 0, biC = 0, biD = 0;

        #pragma unroll
        for (int ph = 0; ph < 2; ++ph) {
            __syncthreads();   // previous phase fully consumed
            // stage 128 rows: linear coalesced global read, permuted LDS write
            {
                const float4* gsrc = (const float4*)cb + ((size_t)(c * kK + ph * 128)) * 32;
                #pragma unroll
                for (int u = 0; u < 8; ++u) {
                    const int gi  = u * kBlock + tid;
                    const int row = gi >> 5, cc = gi & 31;
                    s_cb[row * 32 + (cc & 3) * 8 + (cc >> 2)] = gsrc[gi];
                }
            }
            __syncthreads();

            const int kbase = ph * 128;
            const int cb64  = c * 64 + ph * 32;
            float vA0=0.f,vA1=0.f,vA2=0.f,vA3=0.f, vB0=0.f,vB1=0.f,vB2=0.f,vB3=0.f,
                  vC0=0.f,vC1=0.f,vC2=0.f,vC3=0.f, vD0=0.f,vD1=0.f,vD2=0.f,vD3=0.f;

            // depth-8 pipeline: lane o works group g-o; finals at o==7, g>=7
            #pragma unroll 1
            for (int g = 0; g < 39; ++g) {
                int gg = g - o; gg = gg < 0 ? 0 : (gg > 31 ? 31 : gg);
                const float4* tcr = s_cb + gg * 128 + o;
                float mA0=o?vA0:0.f, mA1=o?vA1:0.f, mA2=o?vA2:0.f, mA3=o?vA3:0.f;
                float mB0=o?vB0:0.f, mB1=o?vB1:0.f, mB2=o?vB2:0.f, mB3=o?vB3:0.f;
                float mC0=o?vC0:0.f, mC1=o?vC1:0.f, mC2=o?vC2:0.f, mC3=o?vC3:0.f;
                float mD0=o?vD0:0.f, mD1=o?vD1:0.f, mD2=o?vD2:0.f, mD3=o?vD3:0.f;
                FOLDROW(0) FOLDROW(1) FOLDROW(2) FOLDROW(3)
                if (o == 7 && g >= 7) {
                    const int gf = g - 7;
                    const float4 bb = s_B4[cb64 + gf];
                    const int kb = kbase + gf * 4;
                    FINX(A, Aa, bestA, biA) FINX(B, Ab, bestB, biB)
                    FINX(C, Ac, bestC, biC) FINX(D, Ad, bestD, biD)
                }
                CSHFL(A) CSHFL(B) CSHFL(C) CSHFL(D)
            }
        }

        const int selA = __shfl(biA, lane | 7);   // broadcast from o==7
        const int selB = __shfl(biB, lane | 7);
        const int selC = __shfl(biC, lane | 7);
        const int selD = __shfl(biD, lane | 7);
        if (c == 0)      { sA0=selA; sB0=selB; sC0=selC; sD0=selD; }
        else if (c == 1) { sA1=selA; sB1=selB; sC1=selC; sD1=selD; }
        else             { sA2=selA; sB2=selB; sC2=selC; sD2=selD; }

        if (c < kNcb - 1) {
            UPDR(A, selA) UPDR(B, selB) UPDR(C, selC) UPDR(D, selD)
            ACOMPUTE(A, Aa) ACOMPUTE(B, Ab) ACOMPUTE(C, Ac) ACOMPUTE(D, Ad)
        }
    }

    // ---- outputs
    float* out_idx = out;                             // (items, 3) as float
    float* out_q   = out + (size_t)kItems * kNcb;     // (items, 128)
    if (o == 0) {
        out_idx[iA*3+0]=(float)sA0; out_idx[iA*3+1]=(float)sA1; out_idx[iA*3+2]=(float)sA2;
        out_idx[iB*3+0]=(float)sB0; out_idx[iB*3+1]=(float)sB1; out_idx[iB*3+2]=(float)sB2;
        out_idx[iC*3+0]=(float)sC0; out_idx[iC*3+1]=(float)sC1; out_idx[iC*3+2]=(float)sC2;
        out_idx[iD*3+0]=(float)sD0; out_idx[iD*3+1]=(float)sD1; out_idx[iD*3+2]=(float)sD2;
    }
    OUTQ(A, sA0, sA1, sA2, iA)
    OUTQ(B, sB0, sB1, sB2, iB)
    OUTQ(C, sC0, sC1, sC2, iC)
    OUTQ(D, sD0, sD1, sD2, iD)
}

extern "C" void kernel_launch(void* const* d_in, const int* in_sizes, int n_in,
                              void* d_out, int out_size, void* d_ws, size_t ws_size,
                              hipStream_t stream) {
    const float* x  = (const float*)d_in[0];
    const float* cb = (const float*)d_in[1];
    float* out = (float*)d_out;
    static bool attr_set = false;
    if (!attr_set) {
        hipFuncSetAttribute((const void*)rvq_kernel,
                            hipFuncAttributeMaxDynamicSharedMemorySize, 65536);
        attr_set = true;
    }
    rvq_kernel<<<kItems / 256, kBlock, 65536, stream>>>(x, cb, out);
}

// Round 10
// 1247.046 us; speedup vs baseline: 1.0275x; 1.0275x over previous
//
#include <hip/hip_runtime.h>
#include <math.h>

// Residual VQ: x (262144,128) fp32, codebooks (3,256,128) fp32.
// Output: [indices as float (262144*3)] ++ [quantized (262144*128)].
//
// ARITHMETIC CONTRACT (round 3, absmax=0 — do not change):
//   M_k  = OpenBLAS sgemm K-loop: sequential FMA chain j=0..127, acc init 0
//   A    = np.sum(r*r): pairwise_sum 8-accumulator scheme, products rounded
//          separately (fmaf(x,x,0) = single-rounded product, blocks fusion)
//   d2_k = (A - 2.0f*M_k) + B_k ; argmin strict < ascending k
//   residual -= q ; quantized = (q0 + q1) + q2  (elementwise fp32, ref order)
//
// ROUND 14: r13 structure, handoff shuffles moved from LDS pipe to DPP.
// Accounting that nails the bottleneck: LDS pipe is CU-SHARED. r11's time
// = 4blk x 8w x 210 steps x 32 ds_read_b128 x 12cyc = 1075us ~= measured
// 1059us (pure LDS-pipe bound). r13 halved reads to 16/step BUT
// __shfl_up(x,1,16) lowers to ds_bpermute = LDS pipe too; CSHFL's 16
// bpermutes/step restored ~32 LDS ops/step + a serial FMA->shfl->select
// dependency -> 1324us. Fix: __shfl_up(.,1,16) IS DPP row_shr:1 (16-lane
// rows): v_mov_b32_dpp, pure VALU, no lgkmcnt. Boundary lanes L%16 in
// {0,8} have o==0 and discard via the existing o?v:0 select (bound_ctrl=1
// zeroes L%16==0 — also discarded); ACOMPUTE consumers have o==r>=1 ->
// bit-exact. Per-codebook __shfl broadcasts (12 total) stay bpermute.
// Everything else identical to r13 (absmax=0 proven): 16:1 FMA:read
// blocking, depth-8 pipeline, permuted-LDS-write staging, waves_per_eu(2,4)
// (delivered VGPR=96, zero spill). Budget: LDS ~571us/CU, VALU ~495us/SIMD
// -> predict 620-800us.

constexpr int kItems = 262144;
constexpr int kDim   = 128;
constexpr int kNcb   = 3;
constexpr int kK     = 256;
constexpr int kBlock = 512;          // 8 waves; 256 items/block

__device__ __forceinline__ float sq_rn(float x) {
    return __builtin_fmaf(x, x, 0.0f);   // single-rounded product, blocks contraction
}
#define F3(a, b, c) __builtin_fmaf((a), (b), (c))

// lane L gets lane L-1's value within each 16-lane row (DPP row_shr:1,
// bound_ctrl=1 -> L%16==0 receives 0). Pure VALU — replaces ds_bpermute.
__device__ __forceinline__ float dpp_shr1(float v) {
    int r = __builtin_amdgcn_update_dpp(
        0, __builtin_bit_cast(int, v), 0x111 /*row_shr:1*/, 0xf, 0xf, true);
    return __builtin_bit_cast(float, r);
}

// ONLY for codebook B_k staging (global reads)
__device__ __forceinline__ float np_sumsq128(const float* __restrict__ p) {
    float a0 = sq_rn(p[0]), a1 = sq_rn(p[1]), a2 = sq_rn(p[2]), a3 = sq_rn(p[3]),
          a4 = sq_rn(p[4]), a5 = sq_rn(p[5]), a6 = sq_rn(p[6]), a7 = sq_rn(p[7]);
    #pragma unroll
    for (int i = 8; i < 128; i += 8) {
        a0 = a0 + sq_rn(p[i + 0]); a1 = a1 + sq_rn(p[i + 1]);
        a2 = a2 + sq_rn(p[i + 2]); a3 = a3 + sq_rn(p[i + 3]);
        a4 = a4 + sq_rn(p[i + 4]); a5 = a5 + sq_rn(p[i + 5]);
        a6 = a6 + sq_rn(p[i + 6]); a7 = a7 + sq_rn(p[i + 7]);
    }
    return ((a0 + a1) + (a2 + a3)) + ((a4 + a5) + (a6 + a7));
}

#define ITEMS(M) M(A) M(B) M(C) M(D)

// residual: 4 items x 4 float4 (dims 16o..16o+15 of each item), all named
#define DECLR(X) float4 R##X##_0, R##X##_1, R##X##_2, R##X##_3;
#define LOADR(X) { const float4* xp_ = (const float4*)(x + i##X * (size_t)kDim) + o * 4; \
  R##X##_0 = xp_[0]; R##X##_1 = xp_[1]; R##X##_2 = xp_[2]; R##X##_3 = xp_[3]; }

// A pairwise-8 local fold: 16 terms ascending local j (=16o+4u+e), acc (4u+e)&7
// (16o % 8 == 0 -> acc index is local)
#define AFOLD2(X) \
  u0=u0+sq_rn(R##X##_0.x); u1=u1+sq_rn(R##X##_0.y); u2=u2+sq_rn(R##X##_0.z); u3=u3+sq_rn(R##X##_0.w); \
  u4=u4+sq_rn(R##X##_1.x); u5=u5+sq_rn(R##X##_1.y); u6=u6+sq_rn(R##X##_1.z); u7=u7+sq_rn(R##X##_1.w); \
  u0=u0+sq_rn(R##X##_2.x); u1=u1+sq_rn(R##X##_2.y); u2=u2+sq_rn(R##X##_2.z); u3=u3+sq_rn(R##X##_2.w); \
  u4=u4+sq_rn(R##X##_3.x); u5=u5+sq_rn(R##X##_3.y); u6=u6+sq_rn(R##X##_3.z); u7=u7+sq_rn(R##X##_3.w);

#define ASHFL() \
  u0=dpp_shr1(u0); u1=dpp_shr1(u1); u2=dpp_shr1(u2); u3=dpp_shr1(u3); \
  u4=dpp_shr1(u4); u5=dpp_shr1(u5); u6=dpp_shr1(u6); u7=dpp_shr1(u7);

// A = np.sum(r*r): 8-round SERIAL handoff along o (exact left fold; lane
// o==r receives lane o==r-1, r>=1 -> DPP boundary lanes never consumed).
// Valid at o==7.
#define ACOMPUTE(X, Avar) { \
  float u0=0.f,u1=0.f,u2=0.f,u3=0.f,u4=0.f,u5=0.f,u6=0.f,u7=0.f; \
  if (o == 0) { AFOLD2(X) } \
  ASHFL() if (o == 1) { AFOLD2(X) } \
  ASHFL() if (o == 2) { AFOLD2(X) } \
  ASHFL() if (o == 3) { AFOLD2(X) } \
  ASHFL() if (o == 4) { AFOLD2(X) } \
  ASHFL() if (o == 5) { AFOLD2(X) } \
  ASHFL() if (o == 6) { AFOLD2(X) } \
  ASHFL() if (o == 7) { AFOLD2(X) } \
  Avar = ((u0 + u1) + (u2 + u3)) + ((u4 + u5) + (u6 + u7)); }

// one tile row rr: 4 shared ds_read_b128 feed 4 items x 16 FMAs (ascending j:
// c_j holds dims 16o+4j..16o+4j+3, paired with R*_j elementwise x,y,z,w)
#define FOLDROW(rr) { \
  const float4 c0 = tcr[(rr)*32 +  0]; \
  const float4 c1 = tcr[(rr)*32 +  8]; \
  const float4 c2 = tcr[(rr)*32 + 16]; \
  const float4 c3 = tcr[(rr)*32 + 24]; \
  mA##rr=F3(RA_0.x,c0.x,mA##rr); mA##rr=F3(RA_0.y,c0.y,mA##rr); mA##rr=F3(RA_0.z,c0.z,mA##rr); mA##rr=F3(RA_0.w,c0.w,mA##rr); \
  mA##rr=F3(RA_1.x,c1.x,mA##rr); mA##rr=F3(RA_1.y,c1.y,mA##rr); mA##rr=F3(RA_1.z,c1.z,mA##rr); mA##rr=F3(RA_1.w,c1.w,mA##rr); \
  mA##rr=F3(RA_2.x,c2.x,mA##rr); mA##rr=F3(RA_2.y,c2.y,mA##rr); mA##rr=F3(RA_2.z,c2.z,mA##rr); mA##rr=F3(RA_2.w,c2.w,mA##rr); \
  mA##rr=F3(RA_3.x,c3.x,mA##rr); mA##rr=F3(RA_3.y,c3.y,mA##rr); mA##rr=F3(RA_3.z,c3.z,mA##rr); mA##rr=F3(RA_3.w,c3.w,mA##rr); \
  mB##rr=F3(RB_0.x,c0.x,mB##rr); mB##rr=F3(RB_0.y,c0.y,mB##rr); mB##rr=F3(RB_0.z,c0.z,mB##rr); mB##rr=F3(RB_0.w,c0.w,mB##rr); \
  mB##rr=F3(RB_1.x,c1.x,mB##rr); mB##rr=F3(RB_1.y,c1.y,mB##rr); mB##rr=F3(RB_1.z,c1.z,mB##rr); mB##rr=F3(RB_1.w,c1.w,mB##rr); \
  mB##rr=F3(RB_2.x,c2.x,mB##rr); mB##rr=F3(RB_2.y,c2.y,mB##rr); mB##rr=F3(RB_2.z,c2.z,mB##rr); mB##rr=F3(RB_2.w,c2.w,mB##rr); \
  mB##rr=F3(RB_3.x,c3.x,mB##rr); mB##rr=F3(RB_3.y,c3.y,mB##rr); mB##rr=F3(RB_3.z,c3.z,mB##rr); mB##rr=F3(RB_3.w,c3.w,mB##rr); \
  mC##rr=F3(RC_0.x,c0.x,mC##rr); mC##rr=F3(RC_0.y,c0.y,mC##rr); mC##rr=F3(RC_0.z,c0.z,mC##rr); mC##rr=F3(RC_0.w,c0.w,mC##rr); \
  mC##rr=F3(RC_1.x,c1.x,mC##rr); mC##rr=F3(RC_1.y,c1.y,mC##rr); mC##rr=F3(RC_1.z,c1.z,mC##rr); mC##rr=F3(RC_1.w,c1.w,mC##rr); \
  mC##rr=F3(RC_2.x,c2.x,mC##rr); mC##rr=F3(RC_2.y,c2.y,mC##rr); mC##rr=F3(RC_2.z,c2.z,mC##rr); mC##rr=F3(RC_2.w,c2.w,mC##rr); \
  mC##rr=F3(RC_3.x,c3.x,mC##rr); mC##rr=F3(RC_3.y,c3.y,mC##rr); mC##rr=F3(RC_3.z,c3.z,mC##rr); mC##rr=F3(RC_3.w,c3.w,mC##rr); \
  mD##rr=F3(RD_0.x,c0.x,mD##rr); mD##rr=F3(RD_0.y,c0.y,mD##rr); mD##rr=F3(RD_0.z,c0.z,mD##rr); mD##rr=F3(RD_0.w,c0.w,mD##rr); \
  mD##rr=F3(RD_1.x,c1.x,mD##rr); mD##rr=F3(RD_1.y,c1.y,mD##rr); mD##rr=F3(RD_1.z,c1.z,mD##rr); mD##rr=F3(RD_1.w,c1.w,mD##rr); \
  mD##rr=F3(RD_2.x,c2.x,mD##rr); mD##rr=F3(RD_2.y,c2.y,mD##rr); mD##rr=F3(RD_2.z,c2.z,mD##rr); mD##rr=F3(RD_2.w,c2.w,mD##rr); \
  mD##rr=F3(RD_3.x,c3.x,mD##rr); mD##rr=F3(RD_3.y,c3.y,mD##rr); mD##rr=F3(RD_3.z,c3.z,mD##rr); mD##rr=F3(RD_3.w,c3.w,mD##rr); }

// finals: ascending k (rr 0..3), strict <; (A-2m)+B bit-safe (2m exact)
#define FINX(X, Avar, bestv, biv) { \
  float d_; \
  d_=(Avar-2.0f*m##X##0)+bb.x; if(d_<bestv){bestv=d_; biv=kb+0;} \
  d_=(Avar-2.0f*m##X##1)+bb.y; if(d_<bestv){bestv=d_; biv=kb+1;} \
  d_=(Avar-2.0f*m##X##2)+bb.z; if(d_<bestv){bestv=d_; biv=kb+2;} \
  d_=(Avar-2.0f*m##X##3)+bb.w; if(d_<bestv){bestv=d_; biv=kb+3;} }

#define CSHFL(X) \
  v##X##0=dpp_shr1(m##X##0); v##X##1=dpp_shr1(m##X##1); \
  v##X##2=dpp_shr1(m##X##2); v##X##3=dpp_shr1(m##X##3);

// residual -= q (elementwise, ref order): this lane's 16 dims of item X
#define UPDR(X, selv) { \
  const float4* cw_ = (const float4*)(cb + ((size_t)c * kK + (selv)) * kDim) + o * 4; \
  R##X##_0.x-=cw_[0].x; R##X##_0.y-=cw_[0].y; R##X##_0.z-=cw_[0].z; R##X##_0.w-=cw_[0].w; \
  R##X##_1.x-=cw_[1].x; R##X##_1.y-=cw_[1].y; R##X##_1.z-=cw_[1].z; R##X##_1.w-=cw_[1].w; \
  R##X##_2.x-=cw_[2].x; R##X##_2.y-=cw_[2].y; R##X##_2.z-=cw_[2].z; R##X##_2.w-=cw_[2].w; \
  R##X##_3.x-=cw_[3].x; R##X##_3.y-=cw_[3].y; R##X##_3.z-=cw_[3].z; R##X##_3.w-=cw_[3].w; }

// quantized output: ((0+q0)+q1)+q2, fp32 elementwise, lane's 16 dims
#define OUTQ(X, s0v, s1v, s2v, itemv) { \
  const float4* g0_ = (const float4*)(cb + ((size_t)0 * kK + (s0v)) * kDim) + o * 4; \
  const float4* g1_ = (const float4*)(cb + ((size_t)1 * kK + (s1v)) * kDim) + o * 4; \
  const float4* g2_ = (const float4*)(cb + ((size_t)2 * kK + (s2v)) * kDim) + o * 4; \
  float4* qo_ = (float4*)(out_q + (itemv) * kDim) + o * 4; \
  _Pragma("unroll") \
  for (int u = 0; u < 4; ++u) { \
    const float4 v0 = g0_[u], v1 = g1_[u], v2 = g2_[u]; \
    float4 w_; \
    w_.x=(v0.x+v1.x)+v2.x; w_.y=(v0.y+v1.y)+v2.y; \
    w_.z=(v0.z+v1.z)+v2.z; w_.w=(v0.w+v1.w)+v2.w; \
    qo_[u]=w_; } }

__global__ __launch_bounds__(kBlock)
__attribute__((amdgpu_waves_per_eu(2, 4)))
void rvq_kernel(
    const float* __restrict__ x,
    const float* __restrict__ cb,
    float* __restrict__ out)
{
    extern __shared__ float4 s_cb[];        // 4096 float4 = 64 KiB: one phase,
                                            // slot = row*32 + (col&3)*8 + (col>>2)
    __shared__ float4 s_B4[kNcb * kK / 4];  // 3 KiB

    const int tid  = threadIdx.x;
    const int lane = tid & 63;
    const int o    = lane & 7;              // dim-eighth 0..7
    const int grp  = lane >> 3;             // item-group 0..7 (4 items each)
    const int wave = tid >> 6;              // 0..7

    // B_k = np.sum(cb*cb, axis=-1), bit-exact
    for (int m = tid; m < kNcb * kK; m += kBlock)
        ((float*)s_B4)[m] = np_sumsq128(cb + (size_t)m * kDim);

    const size_t iA = (size_t)blockIdx.x * 256 + wave * 32 + grp * 4 + 0;
    const size_t iB = iA + 1, iC = iA + 2, iD = iA + 3;

    ITEMS(DECLR)
    ITEMS(LOADR)

    float Aa, Ab, Ac, Ad;
    ACOMPUTE(A, Aa) ACOMPUTE(B, Ab) ACOMPUTE(C, Ac) ACOMPUTE(D, Ad)

    int sA0=0,sA1=0,sA2=0,sB0=0,sB1=0,sB2=0,sC0=0,sC1=0,sC2=0,sD0=0,sD1=0,sD2=0;

    #pragma unroll
    for (int c = 0; c < kNcb; ++c) {
        float bestA = INFINITY, bestB = INFINITY, bestC = INFINITY, bestD = INFINITY;
        int   biA = 0, biB = 0, biC = 0, biD = 0;

        #pragma unroll
        for (int ph = 0; ph < 2; ++ph) {
            __syncthreads();   // previous phase fully consumed
            // stage 128 rows: linear coalesced global read, permuted LDS write
            {
                const float4* gsrc = (const float4*)cb + ((size_t)(c * kK + ph * 128)) * 32;
                #pragma unroll
                for (int u = 0; u < 8; ++u) {
                    const int gi  = u * kBlock + tid;
                    const int row = gi >> 5, cc = gi & 31;
                    s_cb[row * 32 + (cc & 3) * 8 + (cc >> 2)] = gsrc[gi];
                }
            }
            __syncthreads();

            const int kbase = ph * 128;
            const int cb64  = c * 64 + ph * 32;
            float vA0=0.f,vA1=0.f,vA2=0.f,vA3=0.f, vB0=0.f,vB1=0.f,vB2=0.f,vB3=0.f,
                  vC0=0.f,vC1=0.f,vC2=0.f,vC3=0.f, vD0=0.f,vD1=0.f,vD2=0.f,vD3=0.f;

            // depth-8 pipeline: lane o works group g-o; finals at o==7, g>=7
            #pragma unroll 1
            for (int g = 0; g < 39; ++g) {
                int gg = g - o; gg = gg < 0 ? 0 : (gg > 31 ? 31 : gg);
                const float4* tcr = s_cb + gg * 128 + o;
                float mA0=o?vA0:0.f, mA1=o?vA1:0.f, mA2=o?vA2:0.f, mA3=o?vA3:0.f;
                float mB0=o?vB0:0.f, mB1=o?vB1:0.f, mB2=o?vB2:0.f, mB3=o?vB3:0.f;
                float mC0=o?vC0:0.f, mC1=o?vC1:0.f, mC2=o?vC2:0.f, mC3=o?vC3:0.f;
                float mD0=o?vD0:0.f, mD1=o?vD1:0.f, mD2=o?vD2:0.f, mD3=o?vD3:0.f;
                FOLDROW(0) FOLDROW(1) FOLDROW(2) FOLDROW(3)
                if (o == 7 && g >= 7) {
                    const int gf = g - 7;
                    const float4 bb = s_B4[cb64 + gf];
                    const int kb = kbase + gf * 4;
                    FINX(A, Aa, bestA, biA) FINX(B, Ab, bestB, biB)
                    FINX(C, Ac, bestC, biC) FINX(D, Ad, bestD, biD)
                }
                CSHFL(A) CSHFL(B) CSHFL(C) CSHFL(D)
            }
        }

        const int selA = __shfl(biA, lane | 7);   // broadcast from o==7
        const int selB = __shfl(biB, lane | 7);
        const int selC = __shfl(biC, lane | 7);
        const int selD = __shfl(biD, lane | 7);
        if (c == 0)      { sA0=selA; sB0=selB; sC0=selC; sD0=selD; }
        else if (c == 1) { sA1=selA; sB1=selB; sC1=selC; sD1=selD; }
        else             { sA2=selA; sB2=selB; sC2=selC; sD2=selD; }

        if (c < kNcb - 1) {
            UPDR(A, selA) UPDR(B, selB) UPDR(C, selC) UPDR(D, selD)
            ACOMPUTE(A, Aa) ACOMPUTE(B, Ab) ACOMPUTE(C, Ac) ACOMPUTE(D, Ad)
        }
    }

    // ---- outputs
    float* out_idx = out;                             // (items, 3) as float
    float* out_q   = out + (size_t)kItems * kNcb;     // (items, 128)
    if (o == 0) {
        out_idx[iA*3+0]=(float)sA0; out_idx[iA*3+1]=(float)sA1; out_idx[iA*3+2]=(float)sA2;
        out_idx[iB*3+0]=(float)sB0; out_idx[iB*3+1]=(float)sB1; out_idx[iB*3+2]=(float)sB2;
        out_idx[iC*3+0]=(float)sC0; out_idx[iC*3+1]=(float)sC1; out_idx[iC*3+2]=(float)sC2;
        out_idx[iD*3+0]=(float)sD0; out_idx[iD*3+1]=(float)sD1; out_idx[iD*3+2]=(float)sD2;
    }
    OUTQ(A, sA0, sA1, sA2, iA)
    OUTQ(B, sB0, sB1, sB2, iB)
    OUTQ(C, sC0, sC1, sC2, iC)
    OUTQ(D, sD0, sD1, sD2, iD)
}

extern "C" void kernel_launch(void* const* d_in, const int* in_sizes, int n_in,
                              void* d_out, int out_size, void* d_ws, size_t ws_size,
                              hipStream_t stream) {
    const float* x  = (const float*)d_in[0];
    const float* cb = (const float*)d_in[1];
    float* out = (float*)d_out;
    static bool attr_set = false;
    if (!attr_set) {
        hipFuncSetAttribute((const void*)rvq_kernel,
                            hipFuncAttributeMaxDynamicSharedMemorySize, 65536);
        attr_set = true;
    }
    rvq_kernel<<<kItems / 256, kBlock, 65536, stream>>>(x, cb, out);
}

// Round 11
// 1227.018 us; speedup vs baseline: 1.0443x; 1.0163x over previous
//
#include <hip/hip_runtime.h>
#include <math.h>

// Residual VQ: x (262144,128) fp32, codebooks (3,256,128) fp32.
// Output: [indices as float (262144*3)] ++ [quantized (262144*128)].
//
// ARITHMETIC CONTRACT (round 3, absmax=0 — do not change):
//   M_k  = OpenBLAS sgemm K-loop: sequential FMA chain j=0..127, acc init 0
//   A    = np.sum(r*r): pairwise_sum 8-accumulator scheme, products rounded
//          separately (fmaf(x,x,0) = single-rounded product, blocks fusion)
//   d2_k = (A - 2.0f*M_k) + B_k ; argmin strict < ascending k
//   residual -= q ; quantized = (q0 + q1) + q2  (elementwise fp32, ref order)
//
// ROUND 15: r14 byte-identical EXCEPT amdgpu_waves_per_eu(2,4) -> (2,8).
// Evidence: r11 (no attr) ran 40% occupancy (~2 blocks/CU); r12/r13/r14
// (attr max=4) all pinned at 23% (~1 block/CU) across VGPR 128/96/88 and
// two blockings — LDS (67.6K x 2 = 137K <= 160K) and VGPR (88 x 4 waves =
// 352 <= 512) both permit 2 blocks, so the descriptor's max-waves cap is
// the tracked limiter. r14's static model needs only ~50% VALU / ~46% LDS
// pipe yet duration is stuck -> latency-bound at ~1 block/CU: ds_read->FMA
// and staging->barrier edges exposed. min=2 kept (RA budget 256 VGPR; the
// spill-free setting of r13/r14). Expect occupancy ~40%, dur 750-950us.
// Failure read: occupancy stays 23% -> max-cap theory dead; next lever is
// instruction diet (16-lane pipeline, bound_ctrl-free handoff) or r11 revert.

constexpr int kItems = 262144;
constexpr int kDim   = 128;
constexpr int kNcb   = 3;
constexpr int kK     = 256;
constexpr int kBlock = 512;          // 8 waves; 256 items/block

__device__ __forceinline__ float sq_rn(float x) {
    return __builtin_fmaf(x, x, 0.0f);   // single-rounded product, blocks contraction
}
#define F3(a, b, c) __builtin_fmaf((a), (b), (c))

// lane L gets lane L-1's value within each 16-lane row (DPP row_shr:1,
// bound_ctrl=1 -> L%16==0 receives 0). Pure VALU — replaces ds_bpermute.
__device__ __forceinline__ float dpp_shr1(float v) {
    int r = __builtin_amdgcn_update_dpp(
        0, __builtin_bit_cast(int, v), 0x111 /*row_shr:1*/, 0xf, 0xf, true);
    return __builtin_bit_cast(float, r);
}

// ONLY for codebook B_k staging (global reads)
__device__ __forceinline__ float np_sumsq128(const float* __restrict__ p) {
    float a0 = sq_rn(p[0]), a1 = sq_rn(p[1]), a2 = sq_rn(p[2]), a3 = sq_rn(p[3]),
          a4 = sq_rn(p[4]), a5 = sq_rn(p[5]), a6 = sq_rn(p[6]), a7 = sq_rn(p[7]);
    #pragma unroll
    for (int i = 8; i < 128; i += 8) {
        a0 = a0 + sq_rn(p[i + 0]); a1 = a1 + sq_rn(p[i + 1]);
        a2 = a2 + sq_rn(p[i + 2]); a3 = a3 + sq_rn(p[i + 3]);
        a4 = a4 + sq_rn(p[i + 4]); a5 = a5 + sq_rn(p[i + 5]);
        a6 = a6 + sq_rn(p[i + 6]); a7 = a7 + sq_rn(p[i + 7]);
    }
    return ((a0 + a1) + (a2 + a3)) + ((a4 + a5) + (a6 + a7));
}

#define ITEMS(M) M(A) M(B) M(C) M(D)

// residual: 4 items x 4 float4 (dims 16o..16o+15 of each item), all named
#define DECLR(X) float4 R##X##_0, R##X##_1, R##X##_2, R##X##_3;
#define LOADR(X) { const float4* xp_ = (const float4*)(x + i##X * (size_t)kDim) + o * 4; \
  R##X##_0 = xp_[0]; R##X##_1 = xp_[1]; R##X##_2 = xp_[2]; R##X##_3 = xp_[3]; }

// A pairwise-8 local fold: 16 terms ascending local j (=16o+4u+e), acc (4u+e)&7
// (16o % 8 == 0 -> acc index is local)
#define AFOLD2(X) \
  u0=u0+sq_rn(R##X##_0.x); u1=u1+sq_rn(R##X##_0.y); u2=u2+sq_rn(R##X##_0.z); u3=u3+sq_rn(R##X##_0.w); \
  u4=u4+sq_rn(R##X##_1.x); u5=u5+sq_rn(R##X##_1.y); u6=u6+sq_rn(R##X##_1.z); u7=u7+sq_rn(R##X##_1.w); \
  u0=u0+sq_rn(R##X##_2.x); u1=u1+sq_rn(R##X##_2.y); u2=u2+sq_rn(R##X##_2.z); u3=u3+sq_rn(R##X##_2.w); \
  u4=u4+sq_rn(R##X##_3.x); u5=u5+sq_rn(R##X##_3.y); u6=u6+sq_rn(R##X##_3.z); u7=u7+sq_rn(R##X##_3.w);

#define ASHFL() \
  u0=dpp_shr1(u0); u1=dpp_shr1(u1); u2=dpp_shr1(u2); u3=dpp_shr1(u3); \
  u4=dpp_shr1(u4); u5=dpp_shr1(u5); u6=dpp_shr1(u6); u7=dpp_shr1(u7);

// A = np.sum(r*r): 8-round SERIAL handoff along o (exact left fold; lane
// o==r receives lane o==r-1, r>=1 -> DPP boundary lanes never consumed).
// Valid at o==7.
#define ACOMPUTE(X, Avar) { \
  float u0=0.f,u1=0.f,u2=0.f,u3=0.f,u4=0.f,u5=0.f,u6=0.f,u7=0.f; \
  if (o == 0) { AFOLD2(X) } \
  ASHFL() if (o == 1) { AFOLD2(X) } \
  ASHFL() if (o == 2) { AFOLD2(X) } \
  ASHFL() if (o == 3) { AFOLD2(X) } \
  ASHFL() if (o == 4) { AFOLD2(X) } \
  ASHFL() if (o == 5) { AFOLD2(X) } \
  ASHFL() if (o == 6) { AFOLD2(X) } \
  ASHFL() if (o == 7) { AFOLD2(X) } \
  Avar = ((u0 + u1) + (u2 + u3)) + ((u4 + u5) + (u6 + u7)); }

// one tile row rr: 4 shared ds_read_b128 feed 4 items x 16 FMAs (ascending j:
// c_j holds dims 16o+4j..16o+4j+3, paired with R*_j elementwise x,y,z,w)
#define FOLDROW(rr) { \
  const float4 c0 = tcr[(rr)*32 +  0]; \
  const float4 c1 = tcr[(rr)*32 +  8]; \
  const float4 c2 = tcr[(rr)*32 + 16]; \
  const float4 c3 = tcr[(rr)*32 + 24]; \
  mA##rr=F3(RA_0.x,c0.x,mA##rr); mA##rr=F3(RA_0.y,c0.y,mA##rr); mA##rr=F3(RA_0.z,c0.z,mA##rr); mA##rr=F3(RA_0.w,c0.w,mA##rr); \
  mA##rr=F3(RA_1.x,c1.x,mA##rr); mA##rr=F3(RA_1.y,c1.y,mA##rr); mA##rr=F3(RA_1.z,c1.z,mA##rr); mA##rr=F3(RA_1.w,c1.w,mA##rr); \
  mA##rr=F3(RA_2.x,c2.x,mA##rr); mA##rr=F3(RA_2.y,c2.y,mA##rr); mA##rr=F3(RA_2.z,c2.z,mA##rr); mA##rr=F3(RA_2.w,c2.w,mA##rr); \
  mA##rr=F3(RA_3.x,c3.x,mA##rr); mA##rr=F3(RA_3.y,c3.y,mA##rr); mA##rr=F3(RA_3.z,c3.z,mA##rr); mA##rr=F3(RA_3.w,c3.w,mA##rr); \
  mB##rr=F3(RB_0.x,c0.x,mB##rr); mB##rr=F3(RB_0.y,c0.y,mB##rr); mB##rr=F3(RB_0.z,c0.z,mB##rr); mB##rr=F3(RB_0.w,c0.w,mB##rr); \
  mB##rr=F3(RB_1.x,c1.x,mB##rr); mB##rr=F3(RB_1.y,c1.y,mB##rr); mB##rr=F3(RB_1.z,c1.z,mB##rr); mB##rr=F3(RB_1.w,c1.w,mB##rr); \
  mB##rr=F3(RB_2.x,c2.x,mB##rr); mB##rr=F3(RB_2.y,c2.y,mB##rr); mB##rr=F3(RB_2.z,c2.z,mB##rr); mB##rr=F3(RB_2.w,c2.w,mB##rr); \
  mB##rr=F3(RB_3.x,c3.x,mB##rr); mB##rr=F3(RB_3.y,c3.y,mB##rr); mB##rr=F3(RB_3.z,c3.z,mB##rr); mB##rr=F3(RB_3.w,c3.w,mB##rr); \
  mC##rr=F3(RC_0.x,c0.x,mC##rr); mC##rr=F3(RC_0.y,c0.y,mC##rr); mC##rr=F3(RC_0.z,c0.z,mC##rr); mC##rr=F3(RC_0.w,c0.w,mC##rr); \
  mC##rr=F3(RC_1.x,c1.x,mC##rr); mC##rr=F3(RC_1.y,c1.y,mC##rr); mC##rr=F3(RC_1.z,c1.z,mC##rr); mC##rr=F3(RC_1.w,c1.w,mC##rr); \
  mC##rr=F3(RC_2.x,c2.x,mC##rr); mC##rr=F3(RC_2.y,c2.y,mC##rr); mC##rr=F3(RC_2.z,c2.z,mC##rr); mC##rr=F3(RC_2.w,c2.w,mC##rr); \
  mC##rr=F3(RC_3.x,c3.x,mC##rr); mC##rr=F3(RC_3.y,c3.y,mC##rr); mC##rr=F3(RC_3.z,c3.z,mC##rr); mC##rr=F3(RC_3.w,c3.w,mC##rr); \
  mD##rr=F3(RD_0.x,c0.x,mD##rr); mD##rr=F3(RD_0.y,c0.y,mD##rr); mD##rr=F3(RD_0.z,c0.z,mD##rr); mD##rr=F3(RD_0.w,c0.w,mD##rr); \
  mD##rr=F3(RD_1.x,c1.x,mD##rr); mD##rr=F3(RD_1.y,c1.y,mD##rr); mD##rr=F3(RD_1.z,c1.z,mD##rr); mD##rr=F3(RD_1.w,c1.w,mD##rr); \
  mD##rr=F3(RD_2.x,c2.x,mD##rr); mD##rr=F3(RD_2.y,c2.y,mD##rr); mD##rr=F3(RD_2.z,c2.z,mD##rr); mD##rr=F3(RD_2.w,c2.w,mD##rr); \
  mD##rr=F3(RD_3.x,c3.x,mD##rr); mD##rr=F3(RD_3.y,c3.y,mD##rr); mD##rr=F3(RD_3.z,c3.z,mD##rr); mD##rr=F3(RD_3.w,c3.w,mD##rr); }

// finals: ascending k (rr 0..3), strict <; (A-2m)+B bit-safe (2m exact)
#define FINX(X, Avar, bestv, biv) { \
  float d_; \
  d_=(Avar-2.0f*m##X##0)+bb.x; if(d_<bestv){bestv=d_; biv=kb+0;} \
  d_=(Avar-2.0f*m##X##1)+bb.y; if(d_<bestv){bestv=d_; biv=kb+1;} \
  d_=(Avar-2.0f*m##X##2)+bb.z; if(d_<bestv){bestv=d_; biv=kb+2;} \
  d_=(Avar-2.0f*m##X##3)+bb.w; if(d_<bestv){bestv=d_; biv=kb+3;} }

#define CSHFL(X) \
  v##X##0=dpp_shr1(m##X##0); v##X##1=dpp_shr1(m##X##1); \
  v##X##2=dpp_shr1(m##X##2); v##X##3=dpp_shr1(m##X##3);

// residual -= q (elementwise, ref order): this lane's 16 dims of item X
#define UPDR(X, selv) { \
  const float4* cw_ = (const float4*)(cb + ((size_t)c * kK + (selv)) * kDim) + o * 4; \
  R##X##_0.x-=cw_[0].x; R##X##_0.y-=cw_[0].y; R##X##_0.z-=cw_[0].z; R##X##_0.w-=cw_[0].w; \
  R##X##_1.x-=cw_[1].x; R##X##_1.y-=cw_[1].y; R##X##_1.z-=cw_[1].z; R##X##_1.w-=cw_[1].w; \
  R##X##_2.x-=cw_[2].x; R##X##_2.y-=cw_[2].y; R##X##_2.z-=cw_[2].z; R##X##_2.w-=cw_[2].w; \
  R##X##_3.x-=cw_[3].x; R##X##_3.y-=cw_[3].y; R##X##_3.z-=cw_[3].z; R##X##_3.w-=cw_[3].w; }

// quantized output: ((0+q0)+q1)+q2, fp32 elementwise, lane's 16 dims
#define OUTQ(X, s0v, s1v, s2v, itemv) { \
  const float4* g0_ = (const float4*)(cb + ((size_t)0 * kK + (s0v)) * kDim) + o * 4; \
  const float4* g1_ = (const float4*)(cb + ((size_t)1 * kK + (s1v)) * kDim) + o * 4; \
  const float4* g2_ = (const float4*)(cb + ((size_t)2 * kK + (s2v)) * kDim) + o * 4; \
  float4* qo_ = (float4*)(out_q + (itemv) * kDim) + o * 4; \
  _Pragma("unroll") \
  for (int u = 0; u < 4; ++u) { \
    const float4 v0 = g0_[u], v1 = g1_[u], v2 = g2_[u]; \
    float4 w_; \
    w_.x=(v0.x+v1.x)+v2.x; w_.y=(v0.y+v1.y)+v2.y; \
    w_.z=(v0.z+v1.z)+v2.z; w_.w=(v0.w+v1.w)+v2.w; \
    qo_[u]=w_; } }

__global__ __launch_bounds__(kBlock)
__attribute__((amdgpu_waves_per_eu(2, 8)))
void rvq_kernel(
    const float* __restrict__ x,
    const float* __restrict__ cb,
    float* __restrict__ out)
{
    extern __shared__ float4 s_cb[];        // 4096 float4 = 64 KiB: one phase,
                                            // slot = row*32 + (col&3)*8 + (col>>2)
    __shared__ float4 s_B4[kNcb * kK / 4];  // 3 KiB

    const int tid  = threadIdx.x;
    const int lane = tid & 63;
    const int o    = lane & 7;              // dim-eighth 0..7
    const int grp  = lane >> 3;             // item-group 0..7 (4 items each)
    const int wave = tid >> 6;              // 0..7

    // B_k = np.sum(cb*cb, axis=-1), bit-exact
    for (int m = tid; m < kNcb * kK; m += kBlock)
        ((float*)s_B4)[m] = np_sumsq128(cb + (size_t)m * kDim);

    const size_t iA = (size_t)blockIdx.x * 256 + wave * 32 + grp * 4 + 0;
    const size_t iB = iA + 1, iC = iA + 2, iD = iA + 3;

    ITEMS(DECLR)
    ITEMS(LOADR)

    float Aa, Ab, Ac, Ad;
    ACOMPUTE(A, Aa) ACOMPUTE(B, Ab) ACOMPUTE(C, Ac) ACOMPUTE(D, Ad)

    int sA0=0,sA1=0,sA2=0,sB0=0,sB1=0,sB2=0,sC0=0,sC1=0,sC2=0,sD0=0,sD1=0,sD2=0;

    #pragma unroll
    for (int c = 0; c < kNcb; ++c) {
        float bestA = INFINITY, bestB = INFINITY, bestC = INFINITY, bestD = INFINITY;
        int   biA = 0, biB = 0, biC = 0, biD = 0;

        #pragma unroll
        for (int ph = 0; ph < 2; ++ph) {
            __syncthreads();   // previous phase fully consumed
            // stage 128 rows: linear coalesced global read, permuted LDS write
            {
                const float4* gsrc = (const float4*)cb + ((size_t)(c * kK + ph * 128)) * 32;
                #pragma unroll
                for (int u = 0; u < 8; ++u) {
                    const int gi  = u * kBlock + tid;
                    const int row = gi >> 5, cc = gi & 31;
                    s_cb[row * 32 + (cc & 3) * 8 + (cc >> 2)] = gsrc[gi];
                }
            }
            __syncthreads();

            const int kbase = ph * 128;
            const int cb64  = c * 64 + ph * 32;
            float vA0=0.f,vA1=0.f,vA2=0.f,vA3=0.f, vB0=0.f,vB1=0.f,vB2=0.f,vB3=0.f,
                  vC0=0.f,vC1=0.f,vC2=0.f,vC3=0.f, vD0=0.f,vD1=0.f,vD2=0.f,vD3=0.f;

            // depth-8 pipeline: lane o works group g-o; finals at o==7, g>=7
            #pragma unroll 1
            for (int g = 0; g < 39; ++g) {
                int gg = g - o; gg = gg < 0 ? 0 : (gg > 31 ? 31 : gg);
                const float4* tcr = s_cb + gg * 128 + o;
                float mA0=o?vA0:0.f, mA1=o?vA1:0.f, mA2=o?vA2:0.f, mA3=o?vA3:0.f;
                float mB0=o?vB0:0.f, mB1=o?vB1:0.f, mB2=o?vB2:0.f, mB3=o?vB3:0.f;
                float mC0=o?vC0:0.f, mC1=o?vC1:0.f, mC2=o?vC2:0.f, mC3=o?vC3:0.f;
                float mD0=o?vD0:0.f, mD1=o?vD1:0.f, mD2=o?vD2:0.f, mD3=o?vD3:0.f;
                FOLDROW(0) FOLDROW(1) FOLDROW(2) FOLDROW(3)
                if (o == 7 && g >= 7) {
                    const int gf = g - 7;
                    const float4 bb = s_B4[cb64 + gf];
                    const int kb = kbase + gf * 4;
                    FINX(A, Aa, bestA, biA) FINX(B, Ab, bestB, biB)
                    FINX(C, Ac, bestC, biC) FINX(D, Ad, bestD, biD)
                }
                CSHFL(A) CSHFL(B) CSHFL(C) CSHFL(D)
            }
        }

        const int selA = __shfl(biA, lane | 7);   // broadcast from o==7
        const int selB = __shfl(biB, lane | 7);
        const int selC = __shfl(biC, lane | 7);
        const int selD = __shfl(biD, lane | 7);
        if (c == 0)      { sA0=selA; sB0=selB; sC0=selC; sD0=selD; }
        else if (c == 1) { sA1=selA; sB1=selB; sC1=selC; sD1=selD; }
        else             { sA2=selA; sB2=selB; sC2=selC; sD2=selD; }

        if (c < kNcb - 1) {
            UPDR(A, selA) UPDR(B, selB) UPDR(C, selC) UPDR(D, selD)
            ACOMPUTE(A, Aa) ACOMPUTE(B, Ab) ACOMPUTE(C, Ac) ACOMPUTE(D, Ad)
        }
    }

    // ---- outputs
    float* out_idx = out;                             // (items, 3) as float
    float* out_q   = out + (size_t)kItems * kNcb;     // (items, 128)
    if (o == 0) {
        out_idx[iA*3+0]=(float)sA0; out_idx[iA*3+1]=(float)sA1; out_idx[iA*3+2]=(float)sA2;
        out_idx[iB*3+0]=(float)sB0; out_idx[iB*3+1]=(float)sB1; out_idx[iB*3+2]=(float)sB2;
        out_idx[iC*3+0]=(float)sC0; out_idx[iC*3+1]=(float)sC1; out_idx[iC*3+2]=(float)sC2;
        out_idx[iD*3+0]=(float)sD0; out_idx[iD*3+1]=(float)sD1; out_idx[iD*3+2]=(float)sD2;
    }
    OUTQ(A, sA0, sA1, sA2, iA)
    OUTQ(B, sB0, sB1, sB2, iB)
    OUTQ(C, sC0, sC1, sC2, iC)
    OUTQ(D, sD0, sD1, sD2, iD)
}

extern "C" void kernel_launch(void* const* d_in, const int* in_sizes, int n_in,
                              void* d_out, int out_size, void* d_ws, size_t ws_size,
                              hipStream_t stream) {
    const float* x  = (const float*)d_in[0];
    const float* cb = (const float*)d_in[1];
    float* out = (float*)d_out;
    static bool attr_set = false;
    if (!attr_set) {
        hipFuncSetAttribute((const void*)rvq_kernel,
                            hipFuncAttributeMaxDynamicSharedMemorySize, 65536);
        attr_set = true;
    }
    rvq_kernel<<<kItems / 256, kBlock, 65536, stream>>>(x, cb, out);
}

// Round 12
// 973.218 us; speedup vs baseline: 1.3166x; 1.2608x over previous
//
#include <hip/hip_runtime.h>
#include <math.h>

// Residual VQ: x (262144,128) fp32, codebooks (3,256,128) fp32.
// Output: [indices as float (262144*3)] ++ [quantized (262144*128)].
//
// ARITHMETIC CONTRACT (round 3, absmax=0 — do not change):
//   M_k  = OpenBLAS sgemm K-loop: sequential FMA chain j=0..127, acc init 0
//   A    = np.sum(r*r): pairwise_sum 8-accumulator scheme, products rounded
//          separately (fmaf(x,x,0) = single-rounded product, blocks fusion)
//   d2_k = (A - 2.0f*M_k) + B_k ; argmin strict < ascending k
//   residual -= q ; quantized = (q0 + q1) + q2  (elementwise fp32, ref order)
//
// ROUND 16: r11 structure + item-packed v_pk_fma_f32.
// Session-wide accounting: every structure lands at ~1.8-2.2M VALU-busy
// cyc/SIMD for a ~constant FMA instr count -> ~4-4.5 cyc per scalar
// v_fma_f32. m07's 103TF (~3cyc) << 157TF spec corroborates: the spec fp32
// rate is the PACKED rate (v_pk_fma_f32, 2 FMA/lane/instr, MI200 lineage).
// r11 is dual-pipe bound (VALU 70%, LDS pipe ~76%) — moving work between
// pipes (r13-r15) was zero-sum. This round REDUCES both pipes:
//   - the 2 items/lane are packed into f32x2 chains: 1 pk_fma = both items'
//     fmaf for one (row, j). Codebook scalar broadcast to both halves via
//     op_sel (no mov). Each half is bit-exact fmaf; chain order j ascending
//     per row unchanged -> same DAG as r11 (absmax=0 proven).
//   - per-step handoff: __shfl_up (ds_bpermute = LDS pipe) -> DPP row_shr:1
//     (VALU; consumers q>=1, boundary lanes discarded — r14/r15-proven).
//     LDS 40 -> 32 instr/step.
// Everything else r11-verbatim: 2 items x quarter-dims, depth-4 pipeline,
// 35 steps/phase, permuted-LDS-write staging, launch_bounds(512,4), no
// waves_per_eu attr (the only config that reached 40% occupancy).

constexpr int kItems = 262144;
constexpr int kDim   = 128;
constexpr int kNcb   = 3;
constexpr int kK     = 256;
constexpr int kBlock = 512;          // 8 waves; 256 items/block

typedef float f2v __attribute__((ext_vector_type(2)));

__device__ __forceinline__ float sq_rn(float x) {
    return __builtin_fmaf(x, x, 0.0f);   // single-rounded product, blocks contraction
}

// lane L gets lane L-1 within each 16-lane DPP row (row_shr:1, bound_ctrl=1).
// Consumers are q>=1 (L%4!=0 -> L%16!=0), so row boundaries are never read.
__device__ __forceinline__ float dpp_shr1(float v) {
    int r = __builtin_amdgcn_update_dpp(
        0, __builtin_bit_cast(int, v), 0x111 /*row_shr:1*/, 0xf, 0xf, true);
    return __builtin_bit_cast(float, r);
}

// packed FMA: M.lo += P.lo * C.sel ; M.hi += P.hi * C.sel  (per-half fmaf).
// PK_LO uses C's LOW half for both result halves; PK_HI uses C's HIGH half.
#define PK_LO(M, P, C) asm("v_pk_fma_f32 %0, %1, %2, %0 op_sel:[0,0,0] op_sel_hi:[1,0,1]" \
                           : "+v"(M) : "v"(P), "v"(C));
#define PK_HI(M, P, C) asm("v_pk_fma_f32 %0, %1, %2, %0 op_sel:[0,1,0] op_sel_hi:[1,1,1]" \
                           : "+v"(M) : "v"(P), "v"(C));

// ONLY for codebook B_k staging (global reads)
__device__ __forceinline__ float np_sumsq128(const float* __restrict__ p) {
    float a0 = sq_rn(p[0]), a1 = sq_rn(p[1]), a2 = sq_rn(p[2]), a3 = sq_rn(p[3]),
          a4 = sq_rn(p[4]), a5 = sq_rn(p[5]), a6 = sq_rn(p[6]), a7 = sq_rn(p[7]);
    #pragma unroll
    for (int i = 8; i < 128; i += 8) {
        a0 = a0 + sq_rn(p[i + 0]); a1 = a1 + sq_rn(p[i + 1]);
        a2 = a2 + sq_rn(p[i + 2]); a3 = a3 + sq_rn(p[i + 3]);
        a4 = a4 + sq_rn(p[i + 4]); a5 = a5 + sq_rn(p[i + 5]);
        a6 = a6 + sq_rn(p[i + 6]); a7 = a7 + sq_rn(p[i + 7]);
    }
    return ((a0 + a1) + (a2 + a3)) + ((a4 + a5) + (a6 + a7));
}

// ---- residual: 32 packed pairs PRj = (itemA dim j', itemB dim j'), j'=q*32+j
#define PLIST(M) M(0) M(1) M(2) M(3) M(4) M(5) M(6) M(7) \
  M(8) M(9) M(10) M(11) M(12) M(13) M(14) M(15) \
  M(16) M(17) M(18) M(19) M(20) M(21) M(22) M(23) \
  M(24) M(25) M(26) M(27) M(28) M(29) M(30) M(31)
#define DECLP(j) f2v PR##j;

#define ULIST(M) M(0,0,1,2,3) M(1,4,5,6,7) M(2,8,9,10,11) M(3,12,13,14,15) \
  M(4,16,17,18,19) M(5,20,21,22,23) M(6,24,25,26,27) M(7,28,29,30,31)

#define LOADU(u,j0,j1,j2,j3) { const float4 a_ = xa4[u], b_ = xb4[u]; \
  PR##j0 = (f2v){a_.x, b_.x}; PR##j1 = (f2v){a_.y, b_.y}; \
  PR##j2 = (f2v){a_.z, b_.z}; PR##j3 = (f2v){a_.w, b_.w}; }

#define SUBU(u,j0,j1,j2,j3) { const float4 a_ = cwA[u], b_ = cwB[u]; \
  PR##j0.x -= a_.x; PR##j0.y -= b_.x; PR##j1.x -= a_.y; PR##j1.y -= b_.y; \
  PR##j2.x -= a_.z; PR##j2.y -= b_.z; PR##j3.x -= a_.w; PR##j3.y -= b_.w; }

// A = np.sum(r*r) both items at once: term j' -> acc (j'&7), j' ascending.
#define SQ2(P) ((f2v){sq_rn((P).x), sq_rn((P).y)})
#define AFOLDU(u,j0,j1,j2,j3) \
  U##a0_(u) += SQ2(PR##j0); U##a1_(u) += SQ2(PR##j1); \
  U##a2_(u) += SQ2(PR##j2); U##a3_(u) += SQ2(PR##j3);
// acc index base = (u&1)*4 (since (4u+e)&7 = 4(u&1)+e)
#define AFOLDALL() \
  U0+=SQ2(PR0);  U1+=SQ2(PR1);  U2+=SQ2(PR2);  U3+=SQ2(PR3); \
  U4+=SQ2(PR4);  U5+=SQ2(PR5);  U6+=SQ2(PR6);  U7+=SQ2(PR7); \
  U0+=SQ2(PR8);  U1+=SQ2(PR9);  U2+=SQ2(PR10); U3+=SQ2(PR11); \
  U4+=SQ2(PR12); U5+=SQ2(PR13); U6+=SQ2(PR14); U7+=SQ2(PR15); \
  U0+=SQ2(PR16); U1+=SQ2(PR17); U2+=SQ2(PR18); U3+=SQ2(PR19); \
  U4+=SQ2(PR20); U5+=SQ2(PR21); U6+=SQ2(PR22); U7+=SQ2(PR23); \
  U0+=SQ2(PR24); U1+=SQ2(PR25); U2+=SQ2(PR26); U3+=SQ2(PR27); \
  U4+=SQ2(PR28); U5+=SQ2(PR29); U6+=SQ2(PR30); U7+=SQ2(PR31);
#define ASHFLP() \
  U0.x=dpp_shr1(U0.x); U0.y=dpp_shr1(U0.y); U1.x=dpp_shr1(U1.x); U1.y=dpp_shr1(U1.y); \
  U2.x=dpp_shr1(U2.x); U2.y=dpp_shr1(U2.y); U3.x=dpp_shr1(U3.x); U3.y=dpp_shr1(U3.y); \
  U4.x=dpp_shr1(U4.x); U4.y=dpp_shr1(U4.y); U5.x=dpp_shr1(U5.x); U5.y=dpp_shr1(U5.y); \
  U6.x=dpp_shr1(U6.x); U6.y=dpp_shr1(U6.y); U7.x=dpp_shr1(U7.x); U7.y=dpp_shr1(U7.y);
// 4-round serial handoff along q (exact left fold); valid at q==3.
#define ACOMPUTE() { \
  f2v U0={0.f,0.f},U1={0.f,0.f},U2={0.f,0.f},U3={0.f,0.f}, \
      U4={0.f,0.f},U5={0.f,0.f},U6={0.f,0.f},U7={0.f,0.f}; \
  if (q == 0) { AFOLDALL() } \
  ASHFLP() if (q == 1) { AFOLDALL() } \
  ASHFLP() if (q == 2) { AFOLDALL() } \
  ASHFLP() if (q == 3) { AFOLDALL() } \
  const f2v AP_ = ((U0 + U1) + (U2 + U3)) + ((U4 + U5) + (U6 + U7)); \
  Aa = AP_.x; Ab = AP_.y; }

// one quad column u: 4 ds_read_b128 (rows kb..kb+3) feed 2 items x 16 FMAs
// as 16 pk_fma. Per row r chain m_r: e ascending (c.x,c.y,c.z,c.w), u
// ascending across calls -> per-chain order = ascending local j'.
#define FOLD_U(u, Pa, Pb, Pc, Pd) { \
  const float4 c0_ = tc[      (u)*4]; \
  const float4 c1_ = tc[32 + (u)*4]; \
  const float4 c2_ = tc[64 + (u)*4]; \
  const float4 c3_ = tc[96 + (u)*4]; \
  const f2v c0lo = {c0_.x, c0_.y}, c0hi = {c0_.z, c0_.w}; \
  const f2v c1lo = {c1_.x, c1_.y}, c1hi = {c1_.z, c1_.w}; \
  const f2v c2lo = {c2_.x, c2_.y}, c2hi = {c2_.z, c2_.w}; \
  const f2v c3lo = {c3_.x, c3_.y}, c3hi = {c3_.z, c3_.w}; \
  PK_LO(m0, Pa, c0lo) PK_HI(m0, Pb, c0lo) PK_LO(m0, Pc, c0hi) PK_HI(m0, Pd, c0hi) \
  PK_LO(m1, Pa, c1lo) PK_HI(m1, Pb, c1lo) PK_LO(m1, Pc, c1hi) PK_HI(m1, Pd, c1hi) \
  PK_LO(m2, Pa, c2lo) PK_HI(m2, Pb, c2lo) PK_LO(m2, Pc, c2hi) PK_HI(m2, Pd, c2hi) \
  PK_LO(m3, Pa, c3lo) PK_HI(m3, Pb, c3lo) PK_LO(m3, Pc, c3hi) PK_HI(m3, Pd, c3hi) }

__global__ __launch_bounds__(kBlock, 4) void rvq_kernel(
    const float* __restrict__ x,
    const float* __restrict__ cb,
    float* __restrict__ out)
{
    extern __shared__ float4 s_cb[];        // 4096 float4 = 64 KiB (one phase,
                                            // layout [row128][jq8][q4])
    __shared__ float4 s_B4[kNcb * kK / 4];  // 3 KiB

    const int tid  = threadIdx.x;
    const int lane = tid & 63;
    const int p    = lane >> 2;             // pair index 0..15
    const int q    = lane & 3;              // quarter 0..3
    const int wave = tid >> 6;              // 0..7
    const float4* cbv = (const float4*)cb;

    // B_k = np.sum(cb*cb, axis=-1), bit-exact
    for (int m = tid; m < kNcb * kK; m += kBlock)
        ((float*)s_B4)[m] = np_sumsq128(cb + (size_t)m * kDim);

    // items: 2 per 4-lane group, packed lo=A hi=B
    const size_t ia = (size_t)blockIdx.x * 256 + wave * 32 + p * 2 + 0;
    const size_t ib = ia + 1;
    const float4* xa4 = (const float4*)(x + ia * kDim + q * 32);
    const float4* xb4 = (const float4*)(x + ib * kDim + q * 32);

    PLIST(DECLP)
    ULIST(LOADU)

    float Aa, Ab;
    ACOMPUTE()

    int sA0=0,sA1=0,sA2=0,sB0=0,sB1=0,sB2=0;

    #pragma unroll
    for (int c = 0; c < kNcb; ++c) {
        float bestA = INFINITY, bestB = INFINITY;
        int   biA = 0, biB = 0;

        #pragma unroll
        for (int ph = 0; ph < 2; ++ph) {
            __syncthreads();   // previous phase fully consumed
            // stage 128 rows, quarter-interleaved: LDS[row*32 + jq*4 + qq]
            {
                const float4* gsrc = cbv + ((size_t)(c * kK + ph * 128)) * 32;
                #pragma unroll
                for (int u = 0; u < 8; ++u) {
                    const int gi  = u * kBlock + tid;        // coalesced
                    const float4 v = gsrc[gi];
                    const int row = gi >> 5, rem = gi & 31;
                    s_cb[row * 32 + (rem & 7) * 4 + (rem >> 3)] = v;
                }
            }
            __syncthreads();

            const int kbase = ph * 128;
            const int cb64  = c * 64 + ph * 32;
            f2v vm0={0.f,0.f}, vm1={0.f,0.f}, vm2={0.f,0.f}, vm3={0.f,0.f};

            #pragma unroll 1
            for (int g = 0; g < 35; ++g) {
                int gg = g - q; gg = gg < 0 ? 0 : (gg > 31 ? 31 : gg);
                const float4* tc = s_cb + gg * 128 + q;
                f2v m0 = q ? vm0 : (f2v){0.f,0.f}, m1 = q ? vm1 : (f2v){0.f,0.f},
                    m2 = q ? vm2 : (f2v){0.f,0.f}, m3 = q ? vm3 : (f2v){0.f,0.f};
                FOLD_U(0, PR0,PR1,PR2,PR3)
                FOLD_U(1, PR4,PR5,PR6,PR7)
                FOLD_U(2, PR8,PR9,PR10,PR11)
                FOLD_U(3, PR12,PR13,PR14,PR15)
                FOLD_U(4, PR16,PR17,PR18,PR19)
                FOLD_U(5, PR20,PR21,PR22,PR23)
                FOLD_U(6, PR24,PR25,PR26,PR27)
                FOLD_U(7, PR28,PR29,PR30,PR31)
                if (q == 3 && g >= 3) {                      // group g-3 final
                    const int gf = g - 3;
                    const float4 bb = s_B4[cb64 + gf];
                    const int kb = kbase + gf * 4;
                    float d_;
                    d_=(Aa-2.0f*m0.x)+bb.x; if(d_<bestA){bestA=d_;biA=kb+0;}
                    d_=(Aa-2.0f*m1.x)+bb.y; if(d_<bestA){bestA=d_;biA=kb+1;}
                    d_=(Aa-2.0f*m2.x)+bb.z; if(d_<bestA){bestA=d_;biA=kb+2;}
                    d_=(Aa-2.0f*m3.x)+bb.w; if(d_<bestA){bestA=d_;biA=kb+3;}
                    d_=(Ab-2.0f*m0.y)+bb.x; if(d_<bestB){bestB=d_;biB=kb+0;}
                    d_=(Ab-2.0f*m1.y)+bb.y; if(d_<bestB){bestB=d_;biB=kb+1;}
                    d_=(Ab-2.0f*m2.y)+bb.z; if(d_<bestB){bestB=d_;biB=kb+2;}
                    d_=(Ab-2.0f*m3.y)+bb.w; if(d_<bestB){bestB=d_;biB=kb+3;}
                }
                vm0.x=dpp_shr1(m0.x); vm0.y=dpp_shr1(m0.y);
                vm1.x=dpp_shr1(m1.x); vm1.y=dpp_shr1(m1.y);
                vm2.x=dpp_shr1(m2.x); vm2.y=dpp_shr1(m2.y);
                vm3.x=dpp_shr1(m3.x); vm3.y=dpp_shr1(m3.y);
            }
        }

        const int selA = __shfl(biA, lane | 3);   // broadcast from q==3
        const int selB = __shfl(biB, lane | 3);
        if (c == 0) { sA0 = selA; sB0 = selB; }
        else if (c == 1) { sA1 = selA; sB1 = selB; }
        else { sA2 = selA; sB2 = selB; }

        if (c < kNcb - 1) {   // residual -= q (elementwise, ref order); new A
            const float4* cwA = (const float4*)(cb + ((size_t)c*kK + selA)*kDim) + q*8;
            const float4* cwB = (const float4*)(cb + ((size_t)c*kK + selB)*kDim) + q*8;
            ULIST(SUBU)
            ACOMPUTE()
        }
    }

    // ---- outputs
    float* out_idx = out;                             // (items, 3) as float
    float* out_q   = out + (size_t)kItems * kNcb;     // (items, 128)
    if (q == 0) {
        out_idx[ia*3+0] = (float)sA0; out_idx[ia*3+1] = (float)sA1; out_idx[ia*3+2] = (float)sA2;
        out_idx[ib*3+0] = (float)sB0; out_idx[ib*3+1] = (float)sB1; out_idx[ib*3+2] = (float)sB2;
    }
    {
        const float4* g0 = (const float4*)(cb + ((size_t)0*kK + sA0)*kDim) + q*8;
        const float4* g1 = (const float4*)(cb + ((size_t)1*kK + sA1)*kDim) + q*8;
        const float4* g2 = (const float4*)(cb + ((size_t)2*kK + sA2)*kDim) + q*8;
        float4* qo = (float4*)(out_q + ia * kDim) + q*8;
        #pragma unroll
        for (int u = 0; u < 8; ++u) {
            const float4 v0 = g0[u], v1 = g1[u], v2 = g2[u];
            float4 w;
            w.x = (v0.x + v1.x) + v2.x; w.y = (v0.y + v1.y) + v2.y;
            w.z = (v0.z + v1.z) + v2.z; w.w = (v0.w + v1.w) + v2.w;
            qo[u] = w;                 // ((0+q0)+q1)+q2 in fp32, ref order
        }
    }
    {
        const float4* g0 = (const float4*)(cb + ((size_t)0*kK + sB0)*kDim) + q*8;
        const float4* g1 = (const float4*)(cb + ((size_t)1*kK + sB1)*kDim) + q*8;
        const float4* g2 = (const float4*)(cb + ((size_t)2*kK + sB2)*kDim) + q*8;
        float4* qo = (float4*)(out_q + ib * kDim) + q*8;
        #pragma unroll
        for (int u = 0; u < 8; ++u) {
            const float4 v0 = g0[u], v1 = g1[u], v2 = g2[u];
            float4 w;
            w.x = (v0.x + v1.x) + v2.x; w.y = (v0.y + v1.y) + v2.y;
            w.z = (v0.z + v1.z) + v2.z; w.w = (v0.w + v1.w) + v2.w;
            qo[u] = w;
        }
    }
}

extern "C" void kernel_launch(void* const* d_in, const int* in_sizes, int n_in,
                              void* d_out, int out_size, void* d_ws, size_t ws_size,
                              hipStream_t stream) {
    const float* x  = (const float*)d_in[0];
    const float* cb = (const float*)d_in[1];
    float* out = (float*)d_out;
    static bool attr_set = false;
    if (!attr_set) {
        hipFuncSetAttribute((const void*)rvq_kernel,
                            hipFuncAttributeMaxDynamicSharedMemorySize, 65536);
        attr_set = true;
    }
    rvq_kernel<<<kItems / 256, kBlock, 65536, stream>>>(x, cb, out);
}